// Round 1
// baseline (1835.215 us; speedup 1.0000x reference)
//
#include <hip/hip_runtime.h>
#include <hip/hip_bf16.h>

#define N_NODES 100000
#define N_EDGES 3200000
#define D_IN 512
#define D_HID 256
#define D_OUT 64
#define M_PAD 100096  // 782 * 128

typedef __attribute__((ext_vector_type(8))) short bf16x8;
typedef __attribute__((ext_vector_type(4))) float f32x4;

// ---------------- casts ----------------

__global__ void cast_x_kernel(const float* __restrict__ x, __hip_bfloat16* __restrict__ xb) {
    long long i = (long long)blockIdx.x * 256 + threadIdx.x;
    const long long total = (long long)M_PAD * D_IN;
    if (i >= total) return;
    int r = (int)(i / D_IN);
    float v = (r < N_NODES) ? x[i] : 0.f;
    xb[i] = __float2bfloat16(v);
}

// w1 [512][256] -> w1t [256][512] bf16
__global__ void cast_w1t_kernel(const float* __restrict__ w1, __hip_bfloat16* __restrict__ w1t) {
    int i = blockIdx.x * 256 + threadIdx.x;
    if (i >= D_IN * D_HID) return;
    int k = i / D_HID, n = i % D_HID;
    w1t[n * D_IN + k] = __float2bfloat16(w1[i]);
}

// w2 [256][64] -> w2t [64][256] bf16
__global__ void cast_w2t_kernel(const float* __restrict__ w2, __hip_bfloat16* __restrict__ w2t) {
    int i = blockIdx.x * 256 + threadIdx.x;
    if (i >= D_HID * D_OUT) return;
    int k = i / D_OUT, n = i % D_OUT;
    w2t[n * D_HID + k] = __float2bfloat16(w2[i]);
}

__global__ void zero_hb_pad_kernel(__hip_bfloat16* __restrict__ hb) {
    int i = blockIdx.x * 256 + threadIdx.x;
    if (i >= (M_PAD - N_NODES) * D_HID) return;
    hb[(long long)N_NODES * D_HID + i] = __float2bfloat16(0.f);
}

// ---------------- CSR build ----------------

__global__ void hist_kernel(const int* __restrict__ row, int* __restrict__ counts) {
    int e = blockIdx.x * 256 + threadIdx.x;
    if (e >= N_EDGES) return;
    atomicAdd(&counts[row[e]], 1);
}

// single-block exclusive scan of counts -> offsets, cursor (cursor may alias counts)
__global__ void scan_kernel(const int* __restrict__ counts, int* __restrict__ offsets,
                            int* __restrict__ cursor) {
    __shared__ int smem[1024];
    __shared__ int running;
    int t = threadIdx.x;
    if (t == 0) running = 0;
    __syncthreads();
    for (int base = 0; base < N_NODES; base += 1024) {
        int i = base + t;
        int v = (i < N_NODES) ? counts[i] : 0;
        smem[t] = v;
        __syncthreads();
        for (int off = 1; off < 1024; off <<= 1) {
            int u = (t >= off) ? smem[t - off] : 0;
            __syncthreads();
            smem[t] += u;
            __syncthreads();
        }
        int excl = smem[t] - v + running;
        if (i < N_NODES) { offsets[i] = excl; cursor[i] = excl; }
        __syncthreads();
        if (t == 1023) running += smem[1023];
        __syncthreads();
    }
    if (t == 0) offsets[N_NODES] = running;
}

__global__ void scatter_kernel(const int* __restrict__ row, const int* __restrict__ col,
                               const float* __restrict__ ew, int* __restrict__ cursor,
                               int* __restrict__ dst_col, float* __restrict__ dst_w) {
    int e = blockIdx.x * 256 + threadIdx.x;
    if (e >= N_EDGES) return;
    int r = row[e];
    int pos = atomicAdd(&cursor[r], 1);
    dst_col[pos] = col[e];
    dst_w[pos] = ew[e];
}

// ---------------- bf16 MFMA GEMM ----------------
// C[M x N] = A[M x K] * Bt[N x K]^T, A/Bt bf16 row-major, C fp32.
// BM=128, BK=32. Block = 256 threads (4 waves).

template <int BN, int WROWS, int WCOLS, int MT, int NT>
__global__ __launch_bounds__(256) void gemm_bf16_kernel(
    const __hip_bfloat16* __restrict__ A, const __hip_bfloat16* __restrict__ Bt,
    float* __restrict__ C, int K, int Mvalid, int Nld) {
    constexpr int BM = 128;
    constexpr int BK = 32;
    constexpr int LDT = BK + 8;  // pad to break bank conflicts
    __shared__ __align__(16) __hip_bfloat16 As[BM][LDT];
    __shared__ __align__(16) __hip_bfloat16 Bs[BN][LDT];

    const int tid = threadIdx.x;
    const int m0 = blockIdx.x * BM;
    const int n0 = blockIdx.y * BN;
    const int w = tid >> 6, lane = tid & 63;
    const int wr = w % WROWS, wc = w / WROWS;
    const int mbase = wr * MT * 16, nbase = wc * NT * 16;
    const int quad = lane >> 4, l16 = lane & 15;

    f32x4 acc[MT][NT] = {};

    constexpr int ACH = (BM * BK) / (256 * 8);
    constexpr int BCH = (BN * BK) / (256 * 8);

    for (int k0 = 0; k0 < K; k0 += BK) {
#pragma unroll
        for (int c = 0; c < ACH; ++c) {
            int idx = (tid + c * 256) * 8;
            int r = idx / BK, kk = idx % BK;
            *reinterpret_cast<uint4*>(&As[r][kk]) =
                *reinterpret_cast<const uint4*>(&A[(size_t)(m0 + r) * K + k0 + kk]);
        }
#pragma unroll
        for (int c = 0; c < BCH; ++c) {
            int idx = (tid + c * 256) * 8;
            int r = idx / BK, kk = idx % BK;
            *reinterpret_cast<uint4*>(&Bs[r][kk]) =
                *reinterpret_cast<const uint4*>(&Bt[(size_t)(n0 + r) * K + k0 + kk]);
        }
        __syncthreads();

        bf16x8 af[MT], bfr[NT];
#pragma unroll
        for (int mt = 0; mt < MT; ++mt)
            af[mt] = *reinterpret_cast<bf16x8*>(&As[mbase + mt * 16 + l16][quad * 8]);
#pragma unroll
        for (int nt = 0; nt < NT; ++nt)
            bfr[nt] = *reinterpret_cast<bf16x8*>(&Bs[nbase + nt * 16 + l16][quad * 8]);
#pragma unroll
        for (int mt = 0; mt < MT; ++mt)
#pragma unroll
            for (int nt = 0; nt < NT; ++nt)
                acc[mt][nt] = __builtin_amdgcn_mfma_f32_16x16x32_bf16(af[mt], bfr[nt],
                                                                      acc[mt][nt], 0, 0, 0);
        __syncthreads();
    }

#pragma unroll
    for (int mt = 0; mt < MT; ++mt)
#pragma unroll
        for (int nt = 0; nt < NT; ++nt)
#pragma unroll
            for (int r = 0; r < 4; ++r) {
                int rowi = m0 + mbase + mt * 16 + quad * 4 + r;
                int coli = n0 + nbase + nt * 16 + l16;
                if (rowi < Mvalid) C[(size_t)rowi * Nld + coli] = acc[mt][nt][r];
            }
}

// ---------------- aggregation ----------------

// layer 1: h = relu(agg(support1) + b1), written as bf16 (256 dims, 1 node/block)
__global__ __launch_bounds__(256) void agg1_kernel(
    const float* __restrict__ support1, const int* __restrict__ offsets,
    const int* __restrict__ dst_col, const float* __restrict__ dst_w,
    const float* __restrict__ b1, __hip_bfloat16* __restrict__ hb) {
    int n = blockIdx.x;
    int j = threadIdx.x;
    int s = offsets[n], e2 = offsets[n + 1];
    float acc = 0.f;
    for (int e = s; e < e2; ++e) {
        int c = dst_col[e];
        float wv = dst_w[e];
        acc += wv * support1[(size_t)c * D_HID + j];
    }
    acc += b1[j];
    acc = fmaxf(acc, 0.f);
    hb[(size_t)n * D_HID + j] = __float2bfloat16(acc);
}

// layer 2: agg(support2) + b2, then log_softmax over 64 dims. 1 wave per node.
__global__ __launch_bounds__(256) void agg2_softmax_kernel(
    const float* __restrict__ support2, const int* __restrict__ offsets,
    const int* __restrict__ dst_col, const float* __restrict__ dst_w,
    const float* __restrict__ b2, float* __restrict__ out) {
    int n = blockIdx.x * 4 + (threadIdx.x >> 6);
    int j = threadIdx.x & 63;
    if (n >= N_NODES) return;
    int s = offsets[n], e2 = offsets[n + 1];
    float acc = 0.f;
    for (int e = s; e < e2; ++e) {
        int c = dst_col[e];
        float wv = dst_w[e];
        acc += wv * support2[(size_t)c * D_OUT + j];
    }
    acc += b2[j];
    float m = acc;
#pragma unroll
    for (int o = 32; o > 0; o >>= 1) m = fmaxf(m, __shfl_xor(m, o, 64));
    float ex = __expf(acc - m);
    float ssum = ex;
#pragma unroll
    for (int o = 32; o > 0; o >>= 1) ssum += __shfl_xor(ssum, o, 64);
    out[(size_t)n * D_OUT + j] = acc - m - __logf(ssum);
}

// ---------------- launch ----------------

extern "C" void kernel_launch(void* const* d_in, const int* in_sizes, int n_in,
                              void* d_out, int out_size, void* d_ws, size_t ws_size,
                              hipStream_t stream) {
    const float* x  = (const float*)d_in[0];
    const int* row  = (const int*)d_in[1];
    const int* col  = (const int*)d_in[2];
    const float* ew = (const float*)d_in[3];
    const float* w1 = (const float*)d_in[4];
    const float* b1 = (const float*)d_in[5];
    const float* w2 = (const float*)d_in[6];
    const float* b2 = (const float*)d_in[7];
    float* out = (float*)d_out;

    char* ws = (char*)d_ws;
    size_t off = 0;
    auto alloc = [&](size_t bytes) -> void* {
        void* p = ws + off;
        off = (off + bytes + 255) & ~(size_t)255;
        return p;
    };

    __hip_bfloat16* xb  = (__hip_bfloat16*)alloc((size_t)M_PAD * D_IN * 2);   // 102.5 MB
    __hip_bfloat16* w1t = (__hip_bfloat16*)alloc((size_t)D_HID * D_IN * 2);
    __hip_bfloat16* w2t = (__hip_bfloat16*)alloc((size_t)D_OUT * D_HID * 2);
    float* support1     = (float*)alloc((size_t)N_NODES * D_HID * 4);         // 102.4 MB
    __hip_bfloat16* hb  = (__hip_bfloat16*)alloc((size_t)M_PAD * D_HID * 2);  // 51.2 MB
    int* offsets        = (int*)alloc((size_t)(N_NODES + 1) * 4);
    int* cursor         = (int*)alloc((size_t)N_NODES * 4);                   // also counts
    int* dst_col        = (int*)alloc((size_t)N_EDGES * 4);
    float* dst_w        = (float*)alloc((size_t)N_EDGES * 4);
    float* support2     = (float*)xb;  // xb dead after gemm1; reuse (25.6 MB < 102.5 MB)

    // CSR build
    hipMemsetAsync(cursor, 0, (size_t)N_NODES * 4, stream);
    hist_kernel<<<(N_EDGES + 255) / 256, 256, 0, stream>>>(row, cursor);
    scan_kernel<<<1, 1024, 0, stream>>>(cursor, offsets, cursor);
    scatter_kernel<<<(N_EDGES + 255) / 256, 256, 0, stream>>>(row, col, ew, cursor,
                                                              dst_col, dst_w);
    // casts
    cast_x_kernel<<<(M_PAD * D_IN + 255) / 256, 256, 0, stream>>>(x, xb);
    cast_w1t_kernel<<<(D_IN * D_HID + 255) / 256, 256, 0, stream>>>(w1, w1t);
    cast_w2t_kernel<<<(D_HID * D_OUT + 255) / 256, 256, 0, stream>>>(w2, w2t);

    // layer 1
    gemm_bf16_kernel<128, 2, 2, 4, 4><<<dim3(M_PAD / 128, D_HID / 128), 256, 0, stream>>>(
        xb, w1t, support1, D_IN, N_NODES, D_HID);
    agg1_kernel<<<N_NODES, 256, 0, stream>>>(support1, offsets, dst_col, dst_w, b1, hb);
    zero_hb_pad_kernel<<<((M_PAD - N_NODES) * D_HID + 255) / 256, 256, 0, stream>>>(hb);

    // layer 2
    gemm_bf16_kernel<64, 4, 1, 2, 4><<<dim3(M_PAD / 128, 1), 256, 0, stream>>>(
        hb, w2t, support2, D_HID, N_NODES, D_OUT);
    agg2_softmax_kernel<<<(N_NODES + 3) / 4, 256, 0, stream>>>(support2, offsets, dst_col,
                                                               dst_w, b2, out);
}

// Round 2
// 1331.066 us; speedup vs baseline: 1.3788x; 1.3788x over previous
//
#include <hip/hip_runtime.h>
#include <hip/hip_bf16.h>

#define N_NODES 100000
#define N_EDGES 3200000
#define D_IN 512
#define D_HID 256
#define D_OUT 64
#define M_PAD 100096  // 782 * 128

typedef __attribute__((ext_vector_type(8))) short bf16x8;
typedef __attribute__((ext_vector_type(4))) float f32x4;

__device__ __forceinline__ unsigned short f2bf(float f) {
    __hip_bfloat16 h = __float2bfloat16(f);
    return *reinterpret_cast<unsigned short*>(&h);
}
__device__ __forceinline__ float bf_lo(unsigned int v) {  // low bf16 of packed pair
    return __uint_as_float(v << 16);
}
__device__ __forceinline__ float bf_hi(unsigned int v) {  // high bf16 of packed pair
    return __uint_as_float(v & 0xffff0000u);
}

// ---------------- casts ----------------

// 8 elements per thread: 32B fp32 read -> 16B bf16 write
__global__ void cast_x_kernel(const float* __restrict__ x, __hip_bfloat16* __restrict__ xb) {
    long long i8 = ((long long)blockIdx.x * 256 + threadIdx.x) * 8;
    const long long total = (long long)M_PAD * D_IN;
    if (i8 >= total) return;
    int r = (int)(i8 / D_IN);
    ushort4 o0, o1;
    if (r < N_NODES) {
        float4 a = *reinterpret_cast<const float4*>(&x[i8]);
        float4 b = *reinterpret_cast<const float4*>(&x[i8 + 4]);
        o0 = {f2bf(a.x), f2bf(a.y), f2bf(a.z), f2bf(a.w)};
        o1 = {f2bf(b.x), f2bf(b.y), f2bf(b.z), f2bf(b.w)};
    } else {
        o0 = {0, 0, 0, 0};
        o1 = {0, 0, 0, 0};
    }
    *reinterpret_cast<ushort4*>(&xb[i8]) = o0;
    *reinterpret_cast<ushort4*>(&xb[i8 + 4]) = o1;
}

// w1 [512][256] -> w1t [256][512] bf16
__global__ void cast_w1t_kernel(const float* __restrict__ w1, __hip_bfloat16* __restrict__ w1t) {
    int i = blockIdx.x * 256 + threadIdx.x;
    if (i >= D_IN * D_HID) return;
    int k = i / D_HID, n = i % D_HID;
    w1t[n * D_IN + k] = __float2bfloat16(w1[i]);
}

// w2 [256][64] -> w2t [64][256] bf16
__global__ void cast_w2t_kernel(const float* __restrict__ w2, __hip_bfloat16* __restrict__ w2t) {
    int i = blockIdx.x * 256 + threadIdx.x;
    if (i >= D_HID * D_OUT) return;
    int k = i / D_OUT, n = i % D_OUT;
    w2t[n * D_HID + k] = __float2bfloat16(w2[i]);
}

__global__ void zero_hb_pad_kernel(__hip_bfloat16* __restrict__ hb) {
    int i = blockIdx.x * 256 + threadIdx.x;
    if (i >= (M_PAD - N_NODES) * D_HID) return;
    hb[(long long)N_NODES * D_HID + i] = __float2bfloat16(0.f);
}

// ---------------- CSR build ----------------

__global__ void hist_kernel(const int* __restrict__ row, int* __restrict__ counts) {
    int e = blockIdx.x * 256 + threadIdx.x;
    if (e >= N_EDGES) return;
    atomicAdd(&counts[row[e]], 1);
}

// single-block chunked exclusive scan: counts -> offsets, cursor (cursor aliases counts)
__global__ void scan_kernel(const int* __restrict__ counts, int* __restrict__ offsets,
                            int* __restrict__ cursor) {
    __shared__ int sums[1024];
    int t = threadIdx.x;
    const int CH = (N_NODES + 1023) / 1024;  // 98
    int lo = t * CH, hi = min(lo + CH, N_NODES);
    int s = 0;
    for (int i = lo; i < hi; ++i) s += counts[i];
    sums[t] = s;
    __syncthreads();
    for (int off = 1; off < 1024; off <<= 1) {
        int u = (t >= off) ? sums[t - off] : 0;
        __syncthreads();
        sums[t] += u;
        __syncthreads();
    }
    int run = sums[t] - s;  // exclusive prefix of this chunk
    for (int i = lo; i < hi; ++i) {
        int c = counts[i];  // read BEFORE cursor write (aliased)
        offsets[i] = run;
        cursor[i] = run;
        run += c;
    }
    if (t == 1023) offsets[N_NODES] = sums[1023];
}

// pack (col, weight) into int2 for single 8B load per edge
__global__ void scatter_kernel(const int* __restrict__ row, const int* __restrict__ col,
                               const float* __restrict__ ew, int* __restrict__ cursor,
                               int2* __restrict__ edges) {
    int e = blockIdx.x * 256 + threadIdx.x;
    if (e >= N_EDGES) return;
    int r = row[e];
    int pos = atomicAdd(&cursor[r], 1);
    edges[pos] = make_int2(col[e], __float_as_int(ew[e]));
}

// ---------------- bf16 MFMA GEMM ----------------
// C[M x N] = A[M x K] * Bt[N x K]^T, A/Bt bf16 row-major.
// BM=128, BK=32. Block = 256 threads (4 waves). OUT_BF16 selects epilogue dtype.

template <int BN, int WROWS, int WCOLS, int MT, int NT, bool OUT_BF16>
__global__ __launch_bounds__(256) void gemm_bf16_kernel(
    const __hip_bfloat16* __restrict__ A, const __hip_bfloat16* __restrict__ Bt,
    void* __restrict__ Cv, int K, int Mvalid, int Nld) {
    constexpr int BM = 128;
    constexpr int BK = 32;
    constexpr int LDT = BK + 8;  // pad to break bank conflicts
    __shared__ __align__(16) __hip_bfloat16 As[BM][LDT];
    __shared__ __align__(16) __hip_bfloat16 Bs[BN][LDT];

    const int tid = threadIdx.x;
    const int m0 = blockIdx.x * BM;
    const int n0 = blockIdx.y * BN;
    const int w = tid >> 6, lane = tid & 63;
    const int wr = w % WROWS, wc = w / WROWS;
    const int mbase = wr * MT * 16, nbase = wc * NT * 16;
    const int quad = lane >> 4, l16 = lane & 15;

    f32x4 acc[MT][NT] = {};

    constexpr int ACH = (BM * BK) / (256 * 8);
    constexpr int BCH = (BN * BK) / (256 * 8);

    for (int k0 = 0; k0 < K; k0 += BK) {
#pragma unroll
        for (int c = 0; c < ACH; ++c) {
            int idx = (tid + c * 256) * 8;
            int r = idx / BK, kk = idx % BK;
            *reinterpret_cast<uint4*>(&As[r][kk]) =
                *reinterpret_cast<const uint4*>(&A[(size_t)(m0 + r) * K + k0 + kk]);
        }
#pragma unroll
        for (int c = 0; c < BCH; ++c) {
            int idx = (tid + c * 256) * 8;
            int r = idx / BK, kk = idx % BK;
            *reinterpret_cast<uint4*>(&Bs[r][kk]) =
                *reinterpret_cast<const uint4*>(&Bt[(size_t)(n0 + r) * K + k0 + kk]);
        }
        __syncthreads();

        bf16x8 af[MT], bfr[NT];
#pragma unroll
        for (int mt = 0; mt < MT; ++mt)
            af[mt] = *reinterpret_cast<bf16x8*>(&As[mbase + mt * 16 + l16][quad * 8]);
#pragma unroll
        for (int nt = 0; nt < NT; ++nt)
            bfr[nt] = *reinterpret_cast<bf16x8*>(&Bs[nbase + nt * 16 + l16][quad * 8]);
#pragma unroll
        for (int mt = 0; mt < MT; ++mt)
#pragma unroll
            for (int nt = 0; nt < NT; ++nt)
                acc[mt][nt] = __builtin_amdgcn_mfma_f32_16x16x32_bf16(af[mt], bfr[nt],
                                                                      acc[mt][nt], 0, 0, 0);
        __syncthreads();
    }

#pragma unroll
    for (int mt = 0; mt < MT; ++mt)
#pragma unroll
        for (int nt = 0; nt < NT; ++nt)
#pragma unroll
            for (int r = 0; r < 4; ++r) {
                int rowi = m0 + mbase + mt * 16 + quad * 4 + r;
                int coli = n0 + nbase + nt * 16 + l16;
                if (rowi < Mvalid) {
                    if constexpr (OUT_BF16) {
                        ((__hip_bfloat16*)Cv)[(size_t)rowi * Nld + coli] =
                            __float2bfloat16(acc[mt][nt][r]);
                    } else {
                        ((float*)Cv)[(size_t)rowi * Nld + coli] = acc[mt][nt][r];
                    }
                }
            }
}

// ---------------- aggregation ----------------

// layer 1: h = relu(agg(support1b) + b1). One wave per node; lane handles 4 bf16 (8B).
__global__ __launch_bounds__(256) void agg1_kernel(
    const unsigned short* __restrict__ sup,  // bf16 bits [N_NODES][256]
    const int* __restrict__ offsets, const int2* __restrict__ edges,
    const float* __restrict__ b1, __hip_bfloat16* __restrict__ hb) {
    int n = blockIdx.x * 4 + (threadIdx.x >> 6);
    int lane = threadIdx.x & 63;
    if (n >= N_NODES) return;
    int s = offsets[n], e2 = offsets[n + 1];
    float a0 = 0.f, a1 = 0.f, a2 = 0.f, a3 = 0.f;
    const int coloff = lane * 4;
    int e = s;
    for (; e + 4 <= e2; e += 4) {
        int2 m0 = edges[e], m1 = edges[e + 1], m2 = edges[e + 2], m3 = edges[e + 3];
        uint2 v0 = *reinterpret_cast<const uint2*>(sup + (size_t)m0.x * D_HID + coloff);
        uint2 v1 = *reinterpret_cast<const uint2*>(sup + (size_t)m1.x * D_HID + coloff);
        uint2 v2 = *reinterpret_cast<const uint2*>(sup + (size_t)m2.x * D_HID + coloff);
        uint2 v3 = *reinterpret_cast<const uint2*>(sup + (size_t)m3.x * D_HID + coloff);
        float w0 = __int_as_float(m0.y), w1 = __int_as_float(m1.y);
        float w2 = __int_as_float(m2.y), w3 = __int_as_float(m3.y);
        a0 += w0 * bf_lo(v0.x); a1 += w0 * bf_hi(v0.x); a2 += w0 * bf_lo(v0.y); a3 += w0 * bf_hi(v0.y);
        a0 += w1 * bf_lo(v1.x); a1 += w1 * bf_hi(v1.x); a2 += w1 * bf_lo(v1.y); a3 += w1 * bf_hi(v1.y);
        a0 += w2 * bf_lo(v2.x); a1 += w2 * bf_hi(v2.x); a2 += w2 * bf_lo(v2.y); a3 += w2 * bf_hi(v2.y);
        a0 += w3 * bf_lo(v3.x); a1 += w3 * bf_hi(v3.x); a2 += w3 * bf_lo(v3.y); a3 += w3 * bf_hi(v3.y);
    }
    for (; e < e2; ++e) {
        int2 m = edges[e];
        uint2 v = *reinterpret_cast<const uint2*>(sup + (size_t)m.x * D_HID + coloff);
        float wv = __int_as_float(m.y);
        a0 += wv * bf_lo(v.x); a1 += wv * bf_hi(v.x); a2 += wv * bf_lo(v.y); a3 += wv * bf_hi(v.y);
    }
    float4 bb = reinterpret_cast<const float4*>(b1)[lane];
    ushort4 o;
    o.x = f2bf(fmaxf(a0 + bb.x, 0.f));
    o.y = f2bf(fmaxf(a1 + bb.y, 0.f));
    o.z = f2bf(fmaxf(a2 + bb.z, 0.f));
    o.w = f2bf(fmaxf(a3 + bb.w, 0.f));
    *reinterpret_cast<ushort4*>(&hb[(size_t)n * D_HID + coloff]) = o;
}

// layer 2: agg(support2) + b2, then log_softmax over 64 dims. One wave per node.
__global__ __launch_bounds__(256) void agg2_softmax_kernel(
    const float* __restrict__ support2, const int* __restrict__ offsets,
    const int2* __restrict__ edges, const float* __restrict__ b2, float* __restrict__ out) {
    int n = blockIdx.x * 4 + (threadIdx.x >> 6);
    int j = threadIdx.x & 63;
    if (n >= N_NODES) return;
    int s = offsets[n], e2 = offsets[n + 1];
    float acc = 0.f;
    int e = s;
    for (; e + 4 <= e2; e += 4) {
        int2 m0 = edges[e], m1 = edges[e + 1], m2 = edges[e + 2], m3 = edges[e + 3];
        float v0 = support2[(size_t)m0.x * D_OUT + j];
        float v1 = support2[(size_t)m1.x * D_OUT + j];
        float v2 = support2[(size_t)m2.x * D_OUT + j];
        float v3 = support2[(size_t)m3.x * D_OUT + j];
        acc += __int_as_float(m0.y) * v0;
        acc += __int_as_float(m1.y) * v1;
        acc += __int_as_float(m2.y) * v2;
        acc += __int_as_float(m3.y) * v3;
    }
    for (; e < e2; ++e) {
        int2 m = edges[e];
        acc += __int_as_float(m.y) * support2[(size_t)m.x * D_OUT + j];
    }
    acc += b2[j];
    float m = acc;
#pragma unroll
    for (int o = 32; o > 0; o >>= 1) m = fmaxf(m, __shfl_xor(m, o, 64));
    float ex = __expf(acc - m);
    float ssum = ex;
#pragma unroll
    for (int o = 32; o > 0; o >>= 1) ssum += __shfl_xor(ssum, o, 64);
    out[(size_t)n * D_OUT + j] = acc - m - __logf(ssum);
}

// ---------------- launch ----------------

extern "C" void kernel_launch(void* const* d_in, const int* in_sizes, int n_in,
                              void* d_out, int out_size, void* d_ws, size_t ws_size,
                              hipStream_t stream) {
    const float* x  = (const float*)d_in[0];
    const int* row  = (const int*)d_in[1];
    const int* col  = (const int*)d_in[2];
    const float* ew = (const float*)d_in[3];
    const float* w1 = (const float*)d_in[4];
    const float* b1 = (const float*)d_in[5];
    const float* w2 = (const float*)d_in[6];
    const float* b2 = (const float*)d_in[7];
    float* out = (float*)d_out;

    char* ws = (char*)d_ws;
    size_t off = 0;
    auto alloc = [&](size_t bytes) -> void* {
        void* p = ws + off;
        off = (off + bytes + 255) & ~(size_t)255;
        return p;
    };

    __hip_bfloat16* xb   = (__hip_bfloat16*)alloc((size_t)M_PAD * D_IN * 2);   // 102.5 MB
    __hip_bfloat16* w1t  = (__hip_bfloat16*)alloc((size_t)D_HID * D_IN * 2);
    __hip_bfloat16* w2t  = (__hip_bfloat16*)alloc((size_t)D_OUT * D_HID * 2);
    __hip_bfloat16* sup1 = (__hip_bfloat16*)alloc((size_t)N_NODES * D_HID * 2); // 51.2 MB
    __hip_bfloat16* hb   = (__hip_bfloat16*)alloc((size_t)M_PAD * D_HID * 2);   // 51.2 MB
    int* offsets         = (int*)alloc((size_t)(N_NODES + 1) * 4);
    int* cursor          = (int*)alloc((size_t)N_NODES * 4);                    // also counts
    int2* edges          = (int2*)alloc((size_t)N_EDGES * 8);                   // 25.6 MB
    float* support2      = (float*)xb;  // xb dead after gemm1 (25.6 MB < 102.5 MB)

    // CSR build
    hipMemsetAsync(cursor, 0, (size_t)N_NODES * 4, stream);
    hist_kernel<<<(N_EDGES + 255) / 256, 256, 0, stream>>>(row, cursor);
    scan_kernel<<<1, 1024, 0, stream>>>(cursor, offsets, cursor);
    scatter_kernel<<<(N_EDGES + 255) / 256, 256, 0, stream>>>(row, col, ew, cursor, edges);

    // casts
    cast_x_kernel<<<(M_PAD * D_IN / 8 + 255) / 256, 256, 0, stream>>>(x, xb);
    cast_w1t_kernel<<<(D_IN * D_HID + 255) / 256, 256, 0, stream>>>(w1, w1t);
    cast_w2t_kernel<<<(D_HID * D_OUT + 255) / 256, 256, 0, stream>>>(w2, w2t);

    // layer 1: support1b (bf16) = xb @ w1t^T ; hb = relu(agg + b1)
    gemm_bf16_kernel<128, 2, 2, 4, 4, true><<<dim3(M_PAD / 128, D_HID / 128), 256, 0, stream>>>(
        xb, w1t, sup1, D_IN, N_NODES, D_HID);
    agg1_kernel<<<(N_NODES + 3) / 4, 256, 0, stream>>>((const unsigned short*)sup1, offsets,
                                                       edges, b1, hb);
    zero_hb_pad_kernel<<<((M_PAD - N_NODES) * D_HID + 255) / 256, 256, 0, stream>>>(hb);

    // layer 2: support2 (fp32) = hb @ w2t^T ; out = log_softmax(agg + b2)
    gemm_bf16_kernel<64, 4, 1, 2, 4, false><<<dim3(M_PAD / 128, 1), 256, 0, stream>>>(
        hb, w2t, support2, D_HID, N_NODES, D_OUT);
    agg2_softmax_kernel<<<(N_NODES + 3) / 4, 256, 0, stream>>>(support2, offsets, edges, b2, out);
}

// Round 3
// 846.829 us; speedup vs baseline: 2.1672x; 1.5718x over previous
//
#include <hip/hip_runtime.h>
#include <hip/hip_bf16.h>

#define N_NODES 100000
#define N_EDGES 3200000
#define D_IN 512
#define D_HID 256
#define D_OUT 64
#define M_PAD 100096  // 782 * 128

#define NB 782    // row buckets of 128 rows (row >> 7)
#define EPB 8192  // edges per binning block
#define NBLK_BIN ((N_EDGES + EPB - 1) / EPB)  // 391

typedef __attribute__((ext_vector_type(8))) short bf16x8;
typedef __attribute__((ext_vector_type(4))) float f32x4;

__device__ __forceinline__ unsigned short f2bf(float f) {
    __hip_bfloat16 h = __float2bfloat16(f);
    return *reinterpret_cast<unsigned short*>(&h);
}
__device__ __forceinline__ float bf_lo(unsigned int v) { return __uint_as_float(v << 16); }
__device__ __forceinline__ float bf_hi(unsigned int v) { return __uint_as_float(v & 0xffff0000u); }

// ---------------- casts ----------------

__global__ void cast_x_kernel(const float* __restrict__ x, __hip_bfloat16* __restrict__ xb) {
    long long i8 = ((long long)blockIdx.x * 256 + threadIdx.x) * 8;
    const long long total = (long long)M_PAD * D_IN;
    if (i8 >= total) return;
    int r = (int)(i8 / D_IN);
    ushort4 o0, o1;
    if (r < N_NODES) {
        float4 a = *reinterpret_cast<const float4*>(&x[i8]);
        float4 b = *reinterpret_cast<const float4*>(&x[i8 + 4]);
        o0 = {f2bf(a.x), f2bf(a.y), f2bf(a.z), f2bf(a.w)};
        o1 = {f2bf(b.x), f2bf(b.y), f2bf(b.z), f2bf(b.w)};
    } else {
        o0 = {0, 0, 0, 0};
        o1 = {0, 0, 0, 0};
    }
    *reinterpret_cast<ushort4*>(&xb[i8]) = o0;
    *reinterpret_cast<ushort4*>(&xb[i8 + 4]) = o1;
}

__global__ void cast_w1t_kernel(const float* __restrict__ w1, __hip_bfloat16* __restrict__ w1t) {
    int i = blockIdx.x * 256 + threadIdx.x;
    if (i >= D_IN * D_HID) return;
    int k = i / D_HID, n = i % D_HID;
    w1t[n * D_IN + k] = __float2bfloat16(w1[i]);
}

__global__ void cast_w2t_kernel(const float* __restrict__ w2, __hip_bfloat16* __restrict__ w2t) {
    int i = blockIdx.x * 256 + threadIdx.x;
    if (i >= D_HID * D_OUT) return;
    int k = i / D_OUT, n = i % D_OUT;
    w2t[n * D_HID + k] = __float2bfloat16(w2[i]);
}

// ---------------- CSR build (two-phase binned) ----------------

// bucket histogram: LDS hist per block, one global atomic per bucket per block
__global__ __launch_bounds__(256) void hist_bucket_kernel(const int* __restrict__ row,
                                                          int* __restrict__ gcnt) {
    __shared__ int cnt[NB];
    for (int i = threadIdx.x; i < NB; i += 256) cnt[i] = 0;
    __syncthreads();
    int base = blockIdx.x * EPB;
    for (int i = threadIdx.x; i < EPB; i += 256) {
        int e = base + i;
        if (e < N_EDGES) atomicAdd(&cnt[row[e] >> 7], 1);
    }
    __syncthreads();
    for (int i = threadIdx.x; i < NB; i += 256) {
        int c = cnt[i];
        if (c) atomicAdd(&gcnt[i], c);
    }
}

// scan of NB bucket counts -> boff (NB+1), gcur (=boff), offsets[N_NODES]=N_EDGES
__global__ void scan_nb_kernel(const int* __restrict__ gcnt, int* __restrict__ boff,
                               int* __restrict__ gcur, int* __restrict__ offsets) {
    __shared__ int smem[1024];
    int t = threadIdx.x;
    int v = (t < NB) ? gcnt[t] : 0;
    smem[t] = v;
    __syncthreads();
    for (int off = 1; off < 1024; off <<= 1) {
        int u = (t >= off) ? smem[t - off] : 0;
        __syncthreads();
        smem[t] += u;
        __syncthreads();
    }
    int excl = smem[t] - v;
    if (t < NB) { boff[t] = excl; gcur[t] = excl; }
    if (t == 1023) boff[NB] = smem[1023];
    if (t == 0) offsets[N_NODES] = N_EDGES;
}

// bin edges into buckets; payload packs (col<<7)|r_local (24 bits) + weight
__global__ __launch_bounds__(256) void bin_kernel(const int* __restrict__ row,
                                                  const int* __restrict__ col,
                                                  const float* __restrict__ ew,
                                                  int* __restrict__ gcur,
                                                  int2* __restrict__ bucketed) {
    __shared__ int cnt[NB];
    __shared__ int cur[NB];
    for (int i = threadIdx.x; i < NB; i += 256) cnt[i] = 0;
    __syncthreads();
    int base = blockIdx.x * EPB;
    for (int i = threadIdx.x; i < EPB; i += 256) {
        int e = base + i;
        if (e < N_EDGES) atomicAdd(&cnt[row[e] >> 7], 1);
    }
    __syncthreads();
    for (int i = threadIdx.x; i < NB; i += 256) {
        int c = cnt[i];
        cur[i] = c ? atomicAdd(&gcur[i], c) : 0;
    }
    __syncthreads();
    for (int i = threadIdx.x; i < EPB; i += 256) {
        int e = base + i;
        if (e < N_EDGES) {
            int r = row[e];
            int b = r >> 7;
            int pos = atomicAdd(&cur[b], 1);  // global position in bucketed[]
            bucketed[pos] = make_int2((col[e] << 7) | (r & 127), __float_as_int(ew[e]));
        }
    }
}

// per-bucket: local 128-row hist + scan -> offsets[]; scatter to final CSR (32KB window)
__global__ __launch_bounds__(256) void csr_kernel(const int2* __restrict__ bucketed,
                                                  const int* __restrict__ boff,
                                                  int* __restrict__ offsets,
                                                  int2* __restrict__ edges) {
    __shared__ int rcnt[128];
    __shared__ int sc[128];
    __shared__ int rcur[128];
    int b = blockIdx.x;
    int t = threadIdx.x;
    int s = boff[b], e2 = boff[b + 1];
    if (t < 128) rcnt[t] = 0;
    __syncthreads();
    for (int i = s + t; i < e2; i += 256) atomicAdd(&rcnt[bucketed[i].x & 127], 1);
    __syncthreads();
    if (t < 128) sc[t] = rcnt[t];
    __syncthreads();
    for (int off = 1; off < 128; off <<= 1) {
        int u = 0;
        if (t < 128 && t >= off) u = sc[t - off];
        __syncthreads();
        if (t < 128) sc[t] += u;
        __syncthreads();
    }
    if (t < 128) {
        int excl = sc[t] - rcnt[t];
        rcur[t] = excl;
        int rglob = b * 128 + t;
        if (rglob < N_NODES) offsets[rglob] = s + excl;
    }
    __syncthreads();
    for (int i = s + t; i < e2; i += 256) {
        int2 p = bucketed[i];
        int r = p.x & 127;
        int pos = atomicAdd(&rcur[r], 1);
        edges[s + pos] = make_int2(p.x >> 7, p.y);
    }
}

// ---------------- bf16 MFMA GEMM ----------------

template <int BN, int WROWS, int WCOLS, int MT, int NT, bool OUT_BF16>
__global__ __launch_bounds__(256) void gemm_bf16_kernel(
    const __hip_bfloat16* __restrict__ A, const __hip_bfloat16* __restrict__ Bt,
    void* __restrict__ Cv, int K, int Mvalid, int Nld) {
    constexpr int BM = 128;
    constexpr int BK = 32;
    constexpr int LDT = BK + 8;
    __shared__ __align__(16) __hip_bfloat16 As[BM][LDT];
    __shared__ __align__(16) __hip_bfloat16 Bs[BN][LDT];

    const int tid = threadIdx.x;
    const int m0 = blockIdx.x * BM;
    const int n0 = blockIdx.y * BN;
    const int w = tid >> 6, lane = tid & 63;
    const int wr = w % WROWS, wc = w / WROWS;
    const int mbase = wr * MT * 16, nbase = wc * NT * 16;
    const int quad = lane >> 4, l16 = lane & 15;

    f32x4 acc[MT][NT] = {};

    constexpr int ACH = (BM * BK) / (256 * 8);
    constexpr int BCH = (BN * BK) / (256 * 8);

    for (int k0 = 0; k0 < K; k0 += BK) {
#pragma unroll
        for (int c = 0; c < ACH; ++c) {
            int idx = (tid + c * 256) * 8;
            int r = idx / BK, kk = idx % BK;
            *reinterpret_cast<uint4*>(&As[r][kk]) =
                *reinterpret_cast<const uint4*>(&A[(size_t)(m0 + r) * K + k0 + kk]);
        }
#pragma unroll
        for (int c = 0; c < BCH; ++c) {
            int idx = (tid + c * 256) * 8;
            int r = idx / BK, kk = idx % BK;
            *reinterpret_cast<uint4*>(&Bs[r][kk]) =
                *reinterpret_cast<const uint4*>(&Bt[(size_t)(n0 + r) * K + k0 + kk]);
        }
        __syncthreads();

        bf16x8 af[MT], bfr[NT];
#pragma unroll
        for (int mt = 0; mt < MT; ++mt)
            af[mt] = *reinterpret_cast<bf16x8*>(&As[mbase + mt * 16 + l16][quad * 8]);
#pragma unroll
        for (int nt = 0; nt < NT; ++nt)
            bfr[nt] = *reinterpret_cast<bf16x8*>(&Bs[nbase + nt * 16 + l16][quad * 8]);
#pragma unroll
        for (int mt = 0; mt < MT; ++mt)
#pragma unroll
            for (int nt = 0; nt < NT; ++nt)
                acc[mt][nt] = __builtin_amdgcn_mfma_f32_16x16x32_bf16(af[mt], bfr[nt],
                                                                      acc[mt][nt], 0, 0, 0);
        __syncthreads();
    }

#pragma unroll
    for (int mt = 0; mt < MT; ++mt)
#pragma unroll
        for (int nt = 0; nt < NT; ++nt)
#pragma unroll
            for (int r = 0; r < 4; ++r) {
                int rowi = m0 + mbase + mt * 16 + quad * 4 + r;
                int coli = n0 + nbase + nt * 16 + l16;
                if (rowi < Mvalid) {
                    if constexpr (OUT_BF16) {
                        ((__hip_bfloat16*)Cv)[(size_t)rowi * Nld + coli] =
                            __float2bfloat16(acc[mt][nt][r]);
                    } else {
                        ((float*)Cv)[(size_t)rowi * Nld + coli] = acc[mt][nt][r];
                    }
                }
            }
}

// ---------------- aggregation ----------------

// layer 1: hb = relu(agg(sup1) + b1), bf16 out; zero-fills pad rows. One wave per node.
__global__ __launch_bounds__(256) void agg1_kernel(
    const unsigned short* __restrict__ sup, const int* __restrict__ offsets,
    const int2* __restrict__ edges, const float* __restrict__ b1,
    __hip_bfloat16* __restrict__ hb) {
    int n = blockIdx.x * 4 + (threadIdx.x >> 6);
    int lane = threadIdx.x & 63;
    const int coloff = lane * 4;
    if (n >= M_PAD) return;
    if (n >= N_NODES) {
        *reinterpret_cast<ushort4*>(&hb[(size_t)n * D_HID + coloff]) = ushort4{0, 0, 0, 0};
        return;
    }
    int s = offsets[n], e2 = offsets[n + 1];
    float a0 = 0.f, a1 = 0.f, a2 = 0.f, a3 = 0.f;
    int e = s;
    for (; e + 4 <= e2; e += 4) {
        int2 m0 = edges[e], m1 = edges[e + 1], m2 = edges[e + 2], m3 = edges[e + 3];
        uint2 v0 = *reinterpret_cast<const uint2*>(sup + (size_t)m0.x * D_HID + coloff);
        uint2 v1 = *reinterpret_cast<const uint2*>(sup + (size_t)m1.x * D_HID + coloff);
        uint2 v2 = *reinterpret_cast<const uint2*>(sup + (size_t)m2.x * D_HID + coloff);
        uint2 v3 = *reinterpret_cast<const uint2*>(sup + (size_t)m3.x * D_HID + coloff);
        float w0 = __int_as_float(m0.y), w1 = __int_as_float(m1.y);
        float w2 = __int_as_float(m2.y), w3 = __int_as_float(m3.y);
        a0 += w0 * bf_lo(v0.x); a1 += w0 * bf_hi(v0.x); a2 += w0 * bf_lo(v0.y); a3 += w0 * bf_hi(v0.y);
        a0 += w1 * bf_lo(v1.x); a1 += w1 * bf_hi(v1.x); a2 += w1 * bf_lo(v1.y); a3 += w1 * bf_hi(v1.y);
        a0 += w2 * bf_lo(v2.x); a1 += w2 * bf_hi(v2.x); a2 += w2 * bf_lo(v2.y); a3 += w2 * bf_hi(v2.y);
        a0 += w3 * bf_lo(v3.x); a1 += w3 * bf_hi(v3.x); a2 += w3 * bf_lo(v3.y); a3 += w3 * bf_hi(v3.y);
    }
    for (; e < e2; ++e) {
        int2 m = edges[e];
        uint2 v = *reinterpret_cast<const uint2*>(sup + (size_t)m.x * D_HID + coloff);
        float wv = __int_as_float(m.y);
        a0 += wv * bf_lo(v.x); a1 += wv * bf_hi(v.x); a2 += wv * bf_lo(v.y); a3 += wv * bf_hi(v.y);
    }
    float4 bb = reinterpret_cast<const float4*>(b1)[lane];
    ushort4 o;
    o.x = f2bf(fmaxf(a0 + bb.x, 0.f));
    o.y = f2bf(fmaxf(a1 + bb.y, 0.f));
    o.z = f2bf(fmaxf(a2 + bb.z, 0.f));
    o.w = f2bf(fmaxf(a3 + bb.w, 0.f));
    *reinterpret_cast<ushort4*>(&hb[(size_t)n * D_HID + coloff]) = o;
}

// layer 2: agg(sup2 bf16) + b2, log_softmax over 64 dims. One wave per node.
__global__ __launch_bounds__(256) void agg2_softmax_kernel(
    const unsigned short* __restrict__ sup2, const int* __restrict__ offsets,
    const int2* __restrict__ edges, const float* __restrict__ b2, float* __restrict__ out) {
    int n = blockIdx.x * 4 + (threadIdx.x >> 6);
    int j = threadIdx.x & 63;
    if (n >= N_NODES) return;
    int s = offsets[n], e2 = offsets[n + 1];
    float acc = 0.f;
    int e = s;
    for (; e + 4 <= e2; e += 4) {
        int2 m0 = edges[e], m1 = edges[e + 1], m2 = edges[e + 2], m3 = edges[e + 3];
        float v0 = __uint_as_float((unsigned)sup2[(size_t)m0.x * D_OUT + j] << 16);
        float v1 = __uint_as_float((unsigned)sup2[(size_t)m1.x * D_OUT + j] << 16);
        float v2 = __uint_as_float((unsigned)sup2[(size_t)m2.x * D_OUT + j] << 16);
        float v3 = __uint_as_float((unsigned)sup2[(size_t)m3.x * D_OUT + j] << 16);
        acc += __int_as_float(m0.y) * v0;
        acc += __int_as_float(m1.y) * v1;
        acc += __int_as_float(m2.y) * v2;
        acc += __int_as_float(m3.y) * v3;
    }
    for (; e < e2; ++e) {
        int2 m = edges[e];
        acc += __int_as_float(m.y) * __uint_as_float((unsigned)sup2[(size_t)m.x * D_OUT + j] << 16);
    }
    acc += b2[j];
    float m = acc;
#pragma unroll
    for (int o = 32; o > 0; o >>= 1) m = fmaxf(m, __shfl_xor(m, o, 64));
    float ex = __expf(acc - m);
    float ssum = ex;
#pragma unroll
    for (int o = 32; o > 0; o >>= 1) ssum += __shfl_xor(ssum, o, 64);
    out[(size_t)n * D_OUT + j] = acc - m - __logf(ssum);
}

// ---------------- launch ----------------

extern "C" void kernel_launch(void* const* d_in, const int* in_sizes, int n_in,
                              void* d_out, int out_size, void* d_ws, size_t ws_size,
                              hipStream_t stream) {
    const float* x  = (const float*)d_in[0];
    const int* row  = (const int*)d_in[1];
    const int* col  = (const int*)d_in[2];
    const float* ew = (const float*)d_in[3];
    const float* w1 = (const float*)d_in[4];
    const float* b1 = (const float*)d_in[5];
    const float* w2 = (const float*)d_in[6];
    const float* b2 = (const float*)d_in[7];
    float* out = (float*)d_out;

    char* ws = (char*)d_ws;
    size_t off = 0;
    auto alloc = [&](size_t bytes) -> void* {
        void* p = ws + off;
        off = (off + bytes + 255) & ~(size_t)255;
        return p;
    };

    __hip_bfloat16* xb   = (__hip_bfloat16*)alloc((size_t)M_PAD * D_IN * 2);    // 102.5 MB
    __hip_bfloat16* w1t  = (__hip_bfloat16*)alloc((size_t)D_HID * D_IN * 2);
    __hip_bfloat16* w2t  = (__hip_bfloat16*)alloc((size_t)D_OUT * D_HID * 2);
    __hip_bfloat16* sup1 = (__hip_bfloat16*)alloc((size_t)N_NODES * D_HID * 2); // 51.2 MB
    __hip_bfloat16* hb   = (__hip_bfloat16*)alloc((size_t)M_PAD * D_HID * 2);   // 51.2 MB
    int* offsets         = (int*)alloc((size_t)(N_NODES + 1) * 4);
    int* gcnt            = (int*)alloc((size_t)NB * 4);
    int* boff            = (int*)alloc((size_t)(NB + 1) * 4);
    int* gcur            = (int*)alloc((size_t)NB * 4);
    int2* edges          = (int2*)alloc((size_t)N_EDGES * 8);                   // 25.6 MB
    // aliases into xb (dead until cast_x; sup2 after gemm1 epoch):
    int2* bucketed       = (int2*)xb;                 // 25.6 MB, dead after csr_kernel
    unsigned short* sup2 = (unsigned short*)xb;       // 12.8 MB, written by gemm2

    // ---- CSR build (binned two-phase) ----
    hipMemsetAsync(gcnt, 0, (size_t)NB * 4, stream);
    hist_bucket_kernel<<<NBLK_BIN, 256, 0, stream>>>(row, gcnt);
    scan_nb_kernel<<<1, 1024, 0, stream>>>(gcnt, boff, gcur, offsets);
    bin_kernel<<<NBLK_BIN, 256, 0, stream>>>(row, col, ew, gcur, bucketed);
    csr_kernel<<<NB, 256, 0, stream>>>(bucketed, boff, offsets, edges);

    // ---- casts ----
    cast_x_kernel<<<(M_PAD * D_IN / 8 + 255) / 256, 256, 0, stream>>>(x, xb);
    cast_w1t_kernel<<<(D_IN * D_HID + 255) / 256, 256, 0, stream>>>(w1, w1t);
    cast_w2t_kernel<<<(D_HID * D_OUT + 255) / 256, 256, 0, stream>>>(w2, w2t);

    // ---- layer 1 ----
    gemm_bf16_kernel<128, 2, 2, 4, 4, true><<<dim3(M_PAD / 128, D_HID / 128), 256, 0, stream>>>(
        xb, w1t, sup1, D_IN, N_NODES, D_HID);
    agg1_kernel<<<M_PAD / 4, 256, 0, stream>>>((const unsigned short*)sup1, offsets, edges, b1, hb);

    // ---- layer 2 ----
    gemm_bf16_kernel<64, 4, 1, 2, 4, true><<<dim3(M_PAD / 128, 1), 256, 0, stream>>>(
        hb, w2t, (void*)sup2, D_HID, N_NODES, D_OUT);
    agg2_softmax_kernel<<<(N_NODES + 3) / 4, 256, 0, stream>>>(sup2, offsets, edges, b2, out);
}

// Round 4
// 770.250 us; speedup vs baseline: 2.3826x; 1.0994x over previous
//
#include <hip/hip_runtime.h>
#include <hip/hip_bf16.h>
#include <hip/hip_fp8.h>

#define N_NODES 100000
#define N_EDGES 3200000
#define D_IN 512
#define D_HID 256
#define D_OUT 64
#define M_PAD 100096  // 782 * 128

#define NB 782    // row buckets of 128 rows (row >> 7)
#define EPB 8192  // edges per binning block
#define NBLK_BIN ((N_EDGES + EPB - 1) / EPB)  // 391

typedef __attribute__((ext_vector_type(8))) short bf16x8;
typedef __attribute__((ext_vector_type(4))) float f32x4;

__device__ __forceinline__ unsigned short f2bf(float f) {
    __hip_bfloat16 h = __float2bfloat16(f);
    return *reinterpret_cast<unsigned short*>(&h);
}
__device__ __forceinline__ float f8f(unsigned int byte) {  // fp8 e4m3 -> f32 (HW cvt on gfx950)
    __hip_fp8_e4m3 t;
    t.__x = (__hip_fp8_storage_t)byte;
    return (float)t;
}

// ---------------- small casts ----------------

__global__ void cast_w1t_kernel(const float* __restrict__ w1, __hip_bfloat16* __restrict__ w1t) {
    int i = blockIdx.x * 256 + threadIdx.x;
    if (i >= D_IN * D_HID) return;
    int k = i / D_HID, n = i % D_HID;
    w1t[n * D_IN + k] = __float2bfloat16(w1[i]);
}

__global__ void cast_w2t_kernel(const float* __restrict__ w2, __hip_bfloat16* __restrict__ w2t) {
    int i = blockIdx.x * 256 + threadIdx.x;
    if (i >= D_HID * D_OUT) return;
    int k = i / D_OUT, n = i % D_OUT;
    w2t[n * D_HID + k] = __float2bfloat16(w2[i]);
}

// ---------------- CSR build (two-phase binned) ----------------

__global__ __launch_bounds__(256) void hist_bucket_kernel(const int* __restrict__ row,
                                                          int* __restrict__ gcnt) {
    __shared__ int cnt[NB];
    for (int i = threadIdx.x; i < NB; i += 256) cnt[i] = 0;
    __syncthreads();
    int base = blockIdx.x * EPB;
    for (int i = threadIdx.x; i < EPB; i += 256) {
        int e = base + i;
        if (e < N_EDGES) atomicAdd(&cnt[row[e] >> 7], 1);
    }
    __syncthreads();
    for (int i = threadIdx.x; i < NB; i += 256) {
        int c = cnt[i];
        if (c) atomicAdd(&gcnt[i], c);
    }
}

__global__ void scan_nb_kernel(const int* __restrict__ gcnt, int* __restrict__ boff,
                               int* __restrict__ gcur, int* __restrict__ offsets) {
    __shared__ int smem[1024];
    int t = threadIdx.x;
    int v = (t < NB) ? gcnt[t] : 0;
    smem[t] = v;
    __syncthreads();
    for (int off = 1; off < 1024; off <<= 1) {
        int u = (t >= off) ? smem[t - off] : 0;
        __syncthreads();
        smem[t] += u;
        __syncthreads();
    }
    int excl = smem[t] - v;
    if (t < NB) { boff[t] = excl; gcur[t] = excl; }
    if (t == 1023) boff[NB] = smem[1023];
    if (t == 0) offsets[N_NODES] = N_EDGES;
}

__global__ __launch_bounds__(256) void bin_kernel(const int* __restrict__ row,
                                                  const int* __restrict__ col,
                                                  const float* __restrict__ ew,
                                                  int* __restrict__ gcur,
                                                  int2* __restrict__ bucketed) {
    __shared__ int cnt[NB];
    __shared__ int cur[NB];
    for (int i = threadIdx.x; i < NB; i += 256) cnt[i] = 0;
    __syncthreads();
    int base = blockIdx.x * EPB;
    for (int i = threadIdx.x; i < EPB; i += 256) {
        int e = base + i;
        if (e < N_EDGES) atomicAdd(&cnt[row[e] >> 7], 1);
    }
    __syncthreads();
    for (int i = threadIdx.x; i < NB; i += 256) {
        int c = cnt[i];
        cur[i] = c ? atomicAdd(&gcur[i], c) : 0;
    }
    __syncthreads();
    for (int i = threadIdx.x; i < EPB; i += 256) {
        int e = base + i;
        if (e < N_EDGES) {
            int r = row[e];
            int b = r >> 7;
            int pos = atomicAdd(&cur[b], 1);
            bucketed[pos] = make_int2((col[e] << 7) | (r & 127), __float_as_int(ew[e]));
        }
    }
}

__global__ __launch_bounds__(256) void csr_kernel(const int2* __restrict__ bucketed,
                                                  const int* __restrict__ boff,
                                                  int* __restrict__ offsets,
                                                  int2* __restrict__ edges) {
    __shared__ int rcnt[128];
    __shared__ int sc[128];
    __shared__ int rcur[128];
    int b = blockIdx.x;
    int t = threadIdx.x;
    int s = boff[b], e2 = boff[b + 1];
    if (t < 128) rcnt[t] = 0;
    __syncthreads();
    for (int i = s + t; i < e2; i += 256) atomicAdd(&rcnt[bucketed[i].x & 127], 1);
    __syncthreads();
    if (t < 128) sc[t] = rcnt[t];
    __syncthreads();
    for (int off = 1; off < 128; off <<= 1) {
        int u = 0;
        if (t < 128 && t >= off) u = sc[t - off];
        __syncthreads();
        if (t < 128) sc[t] += u;
        __syncthreads();
    }
    if (t < 128) {
        int excl = sc[t] - rcnt[t];
        rcur[t] = excl;
        int rglob = b * 128 + t;
        if (rglob < N_NODES) offsets[rglob] = s + excl;
    }
    __syncthreads();
    for (int i = s + t; i < e2; i += 256) {
        int2 p = bucketed[i];
        int r = p.x & 127;
        int pos = atomicAdd(&rcur[r], 1);
        edges[s + pos] = make_int2(p.x >> 7, p.y);
    }
}

// ---------------- MFMA GEMM ----------------
// C[M x N] = A[M x K] * Bt[N x K]^T. A either bf16 or fp32 (cast during staging).
// OUT_MODE: 0 = fp32, 1 = bf16, 2 = fp8 e4m3.

template <int BN, int WROWS, int WCOLS, int MT, int NT, bool A_F32, int OUT_MODE>
__global__ __launch_bounds__(256) void gemm_bf16_kernel(
    const void* __restrict__ Av, const __hip_bfloat16* __restrict__ Bt,
    void* __restrict__ Cv, int K, int Mvalid, int Nld) {
    constexpr int BM = 128;
    constexpr int BK = 32;
    constexpr int LDT = BK + 8;
    __shared__ __align__(16) __hip_bfloat16 As[BM][LDT];
    __shared__ __align__(16) __hip_bfloat16 Bs[BN][LDT];

    const int tid = threadIdx.x;
    const int m0 = blockIdx.x * BM;
    const int n0 = blockIdx.y * BN;
    const int w = tid >> 6, lane = tid & 63;
    const int wr = w % WROWS, wc = w / WROWS;
    const int mbase = wr * MT * 16, nbase = wc * NT * 16;
    const int quad = lane >> 4, l16 = lane & 15;

    f32x4 acc[MT][NT] = {};

    constexpr int ACH = (BM * BK) / (256 * 8);
    constexpr int BCH = (BN * BK) / (256 * 8);

    for (int k0 = 0; k0 < K; k0 += BK) {
#pragma unroll
        for (int c = 0; c < ACH; ++c) {
            int idx = (tid + c * 256) * 8;
            int r = idx / BK, kk = idx % BK;
            if constexpr (A_F32) {
                int grow = m0 + r;
                uint4 o;
                if (grow < Mvalid) {
                    const float* ap = (const float*)Av + (size_t)grow * K + k0 + kk;
                    float4 f0 = *reinterpret_cast<const float4*>(ap);
                    float4 f1 = *reinterpret_cast<const float4*>(ap + 4);
                    o.x = (unsigned)f2bf(f0.x) | ((unsigned)f2bf(f0.y) << 16);
                    o.y = (unsigned)f2bf(f0.z) | ((unsigned)f2bf(f0.w) << 16);
                    o.z = (unsigned)f2bf(f1.x) | ((unsigned)f2bf(f1.y) << 16);
                    o.w = (unsigned)f2bf(f1.z) | ((unsigned)f2bf(f1.w) << 16);
                } else {
                    o = uint4{0, 0, 0, 0};
                }
                *reinterpret_cast<uint4*>(&As[r][kk]) = o;
            } else {
                *reinterpret_cast<uint4*>(&As[r][kk]) = *reinterpret_cast<const uint4*>(
                    (const __hip_bfloat16*)Av + (size_t)(m0 + r) * K + k0 + kk);
            }
        }
#pragma unroll
        for (int c = 0; c < BCH; ++c) {
            int idx = (tid + c * 256) * 8;
            int r = idx / BK, kk = idx % BK;
            *reinterpret_cast<uint4*>(&Bs[r][kk]) =
                *reinterpret_cast<const uint4*>(&Bt[(size_t)(n0 + r) * K + k0 + kk]);
        }
        __syncthreads();

        bf16x8 af[MT], bfr[NT];
#pragma unroll
        for (int mt = 0; mt < MT; ++mt)
            af[mt] = *reinterpret_cast<bf16x8*>(&As[mbase + mt * 16 + l16][quad * 8]);
#pragma unroll
        for (int nt = 0; nt < NT; ++nt)
            bfr[nt] = *reinterpret_cast<bf16x8*>(&Bs[nbase + nt * 16 + l16][quad * 8]);
#pragma unroll
        for (int mt = 0; mt < MT; ++mt)
#pragma unroll
            for (int nt = 0; nt < NT; ++nt)
                acc[mt][nt] = __builtin_amdgcn_mfma_f32_16x16x32_bf16(af[mt], bfr[nt],
                                                                      acc[mt][nt], 0, 0, 0);
        __syncthreads();
    }

#pragma unroll
    for (int mt = 0; mt < MT; ++mt)
#pragma unroll
        for (int nt = 0; nt < NT; ++nt)
#pragma unroll
            for (int r = 0; r < 4; ++r) {
                int rowi = m0 + mbase + mt * 16 + quad * 4 + r;
                int coli = n0 + nbase + nt * 16 + l16;
                if (rowi < Mvalid) {
                    if constexpr (OUT_MODE == 0) {
                        ((float*)Cv)[(size_t)rowi * Nld + coli] = acc[mt][nt][r];
                    } else if constexpr (OUT_MODE == 1) {
                        ((__hip_bfloat16*)Cv)[(size_t)rowi * Nld + coli] =
                            __float2bfloat16(acc[mt][nt][r]);
                    } else {
                        __hip_fp8_e4m3 q(acc[mt][nt][r]);
                        ((unsigned char*)Cv)[(size_t)rowi * Nld + coli] = q.__x;
                    }
                }
            }
}

// ---------------- aggregation ----------------

// layer 1: hb = relu(agg(sup1 fp8) + b1) -> bf16; zero-fills pad rows. One wave per node.
// Lane handles 4 fp8 (one uint) at cols [4*lane, 4*lane+4).
__global__ __launch_bounds__(256) void agg1_kernel(
    const unsigned int* __restrict__ sup,  // fp8 [N_NODES][256] as uint[N_NODES][64]
    const int* __restrict__ offsets, const int2* __restrict__ edges,
    const float* __restrict__ b1, __hip_bfloat16* __restrict__ hb) {
    int n = blockIdx.x * 4 + (threadIdx.x >> 6);
    int lane = threadIdx.x & 63;
    if (n >= M_PAD) return;
    if (n >= N_NODES) {
        *reinterpret_cast<ushort4*>(&hb[(size_t)n * D_HID + lane * 4]) = ushort4{0, 0, 0, 0};
        return;
    }
    int s = offsets[n], e2 = offsets[n + 1];
    float a0 = 0.f, a1 = 0.f, a2 = 0.f, a3 = 0.f;
    int e = s;
    for (; e + 8 <= e2; e += 8) {
        int2 m[8];
        unsigned int v[8];
#pragma unroll
        for (int i = 0; i < 8; ++i) m[i] = edges[e + i];
#pragma unroll
        for (int i = 0; i < 8; ++i) v[i] = sup[(size_t)m[i].x * 64 + lane];
#pragma unroll
        for (int i = 0; i < 8; ++i) {
            float wv = __int_as_float(m[i].y);
            a0 += wv * f8f(v[i] & 0xff);
            a1 += wv * f8f((v[i] >> 8) & 0xff);
            a2 += wv * f8f((v[i] >> 16) & 0xff);
            a3 += wv * f8f(v[i] >> 24);
        }
    }
    for (; e < e2; ++e) {
        int2 m = edges[e];
        unsigned int v = sup[(size_t)m.x * 64 + lane];
        float wv = __int_as_float(m.y);
        a0 += wv * f8f(v & 0xff);
        a1 += wv * f8f((v >> 8) & 0xff);
        a2 += wv * f8f((v >> 16) & 0xff);
        a3 += wv * f8f(v >> 24);
    }
    float4 bb = reinterpret_cast<const float4*>(b1)[lane];
    ushort4 o;
    o.x = f2bf(fmaxf(a0 + bb.x, 0.f));
    o.y = f2bf(fmaxf(a1 + bb.y, 0.f));
    o.z = f2bf(fmaxf(a2 + bb.z, 0.f));
    o.w = f2bf(fmaxf(a3 + bb.w, 0.f));
    *reinterpret_cast<ushort4*>(&hb[(size_t)n * D_HID + lane * 4]) = o;
}

// layer 2: agg(sup2 bf16) + b2, log_softmax over 64 dims. One wave per node.
__global__ __launch_bounds__(256) void agg2_softmax_kernel(
    const unsigned short* __restrict__ sup2, const int* __restrict__ offsets,
    const int2* __restrict__ edges, const float* __restrict__ b2, float* __restrict__ out) {
    int n = blockIdx.x * 4 + (threadIdx.x >> 6);
    int j = threadIdx.x & 63;
    if (n >= N_NODES) return;
    int s = offsets[n], e2 = offsets[n + 1];
    float acc = 0.f;
    int e = s;
    for (; e + 4 <= e2; e += 4) {
        int2 m0 = edges[e], m1 = edges[e + 1], m2 = edges[e + 2], m3 = edges[e + 3];
        float v0 = __uint_as_float((unsigned)sup2[(size_t)m0.x * D_OUT + j] << 16);
        float v1 = __uint_as_float((unsigned)sup2[(size_t)m1.x * D_OUT + j] << 16);
        float v2 = __uint_as_float((unsigned)sup2[(size_t)m2.x * D_OUT + j] << 16);
        float v3 = __uint_as_float((unsigned)sup2[(size_t)m3.x * D_OUT + j] << 16);
        acc += __int_as_float(m0.y) * v0;
        acc += __int_as_float(m1.y) * v1;
        acc += __int_as_float(m2.y) * v2;
        acc += __int_as_float(m3.y) * v3;
    }
    for (; e < e2; ++e) {
        int2 m = edges[e];
        acc += __int_as_float(m.y) * __uint_as_float((unsigned)sup2[(size_t)m.x * D_OUT + j] << 16);
    }
    acc += b2[j];
    float m = acc;
#pragma unroll
    for (int o = 32; o > 0; o >>= 1) m = fmaxf(m, __shfl_xor(m, o, 64));
    float ex = __expf(acc - m);
    float ssum = ex;
#pragma unroll
    for (int o = 32; o > 0; o >>= 1) ssum += __shfl_xor(ssum, o, 64);
    out[(size_t)n * D_OUT + j] = acc - m - __logf(ssum);
}

// ---------------- launch ----------------

extern "C" void kernel_launch(void* const* d_in, const int* in_sizes, int n_in,
                              void* d_out, int out_size, void* d_ws, size_t ws_size,
                              hipStream_t stream) {
    const float* x  = (const float*)d_in[0];
    const int* row  = (const int*)d_in[1];
    const int* col  = (const int*)d_in[2];
    const float* ew = (const float*)d_in[3];
    const float* w1 = (const float*)d_in[4];
    const float* b1 = (const float*)d_in[5];
    const float* w2 = (const float*)d_in[6];
    const float* b2 = (const float*)d_in[7];
    float* out = (float*)d_out;

    char* ws = (char*)d_ws;
    size_t off = 0;
    auto alloc = [&](size_t bytes) -> void* {
        void* p = ws + off;
        off = (off + bytes + 255) & ~(size_t)255;
        return p;
    };

    __hip_bfloat16* w1t  = (__hip_bfloat16*)alloc((size_t)D_HID * D_IN * 2);
    __hip_bfloat16* w2t  = (__hip_bfloat16*)alloc((size_t)D_OUT * D_HID * 2);
    unsigned char* sup1  = (unsigned char*)alloc((size_t)N_NODES * D_HID);      // fp8, 25.6 MB
    __hip_bfloat16* hb   = (__hip_bfloat16*)alloc((size_t)M_PAD * D_HID * 2);   // 51.2 MB
    unsigned short* sup2 = (unsigned short*)alloc((size_t)N_NODES * D_OUT * 2); // bf16, 12.8 MB
    int* offsets         = (int*)alloc((size_t)(N_NODES + 1) * 4);
    int* gcnt            = (int*)alloc((size_t)NB * 4);
    int* boff            = (int*)alloc((size_t)(NB + 1) * 4);
    int* gcur            = (int*)alloc((size_t)NB * 4);
    int2* edges          = (int2*)alloc((size_t)N_EDGES * 8);                   // 25.6 MB
    int2* bucketed       = (int2*)alloc((size_t)N_EDGES * 8);                   // 25.6 MB

    // ---- CSR build ----
    hipMemsetAsync(gcnt, 0, (size_t)NB * 4, stream);
    hist_bucket_kernel<<<NBLK_BIN, 256, 0, stream>>>(row, gcnt);
    scan_nb_kernel<<<1, 1024, 0, stream>>>(gcnt, boff, gcur, offsets);
    bin_kernel<<<NBLK_BIN, 256, 0, stream>>>(row, col, ew, gcur, bucketed);
    csr_kernel<<<NB, 256, 0, stream>>>(bucketed, boff, offsets, edges);

    // ---- weight casts ----
    cast_w1t_kernel<<<(D_IN * D_HID + 255) / 256, 256, 0, stream>>>(w1, w1t);
    cast_w2t_kernel<<<(D_HID * D_OUT + 255) / 256, 256, 0, stream>>>(w2, w2t);

    // ---- layer 1: sup1(fp8) = bf16(x) @ w1t^T ; hb = relu(agg + b1) ----
    gemm_bf16_kernel<128, 2, 2, 4, 4, true, 2><<<dim3(M_PAD / 128, D_HID / 128), 256, 0, stream>>>(
        x, w1t, sup1, D_IN, N_NODES, D_HID);
    agg1_kernel<<<M_PAD / 4, 256, 0, stream>>>((const unsigned int*)sup1, offsets, edges, b1, hb);

    // ---- layer 2: sup2(bf16) = hb @ w2t^T ; out = log_softmax(agg + b2) ----
    gemm_bf16_kernel<64, 4, 1, 2, 4, false, 1><<<dim3(M_PAD / 128, 1), 256, 0, stream>>>(
        hb, w2t, sup2, D_HID, N_NODES, D_OUT);
    agg2_softmax_kernel<<<(N_NODES + 3) / 4, 256, 0, stream>>>(sup2, offsets, edges, b2, out);
}